// Round 1
// baseline (147.140 us; speedup 1.0000x reference)
//
#include <hip/hip_runtime.h>

#define B_   64
#define DIM  640
#define NPIX 100
#define NCH  25      // float4 chunks per row (100 floats)
#define LDC  32      // padded chunks per row in LDS (bank swizzle headroom)
#define TS   64      // tile size
#define NT   10      // DIM / TS
#define NTP  55      // NT*(NT+1)/2 upper-triangle tile pairs
#define TRI  205120  // DIM*(DIM+1)/2
#define EPS  1e-5f

// Kernel B: per (batch, tile-pair) compute 64x64 dcov tile, write packed triu
// into out, accumulate row sums (dcov symmetric -> tile contributes to rows i
// and rows j).
__global__ __launch_bounds__(256, 2) void dcov_tile_kernel(
    const float* __restrict__ x, const float* __restrict__ temp,
    float* __restrict__ out, float* __restrict__ rowsum)
{
    __shared__ float4 xi4[TS * LDC];
    __shared__ float4 xj4[TS * LDC];
    __shared__ float dI[TS];
    __shared__ float dJ[TS];

    const int t   = threadIdx.x;
    const int blk = blockIdx.x;
    const int b   = blk / NTP;
    int tp = blk % NTP;
    int ti = 0;
    while (tp >= NT - ti) { tp -= NT - ti; ++ti; }
    const int tj = ti + tp;
    const int i0 = ti * TS, j0 = tj * TS;

    const float4* xb4 = reinterpret_cast<const float4*>(x) + (size_t)b * DIM * NCH;

    // Stage tiles: global float4 loads (coalesced), XOR-swizzled LDS layout
    for (int f = t; f < TS * NCH; f += 256) {
        int r = f / NCH, c = f - r * NCH;
        xi4[r * LDC + (c ^ ((r >> 2) & 7))] = xb4[(size_t)(i0 + r) * NCH + c];
    }
    for (int f = t; f < TS * NCH; f += 256) {
        int r = f / NCH, c = f - r * NCH;
        xj4[r * LDC + (c ^ ((r >> 2) & 7))] = xb4[(size_t)(j0 + r) * NCH + c];
    }
    __syncthreads();

    // Per-row sum of squares (gram diagonal)
    if (t < TS) {
        float s = 0.f;
        const int sw = (t >> 2) & 7;
        for (int c = 0; c < NCH; ++c) {
            float4 v = xi4[t * LDC + (c ^ sw)];
            s += v.x * v.x + v.y * v.y + v.z * v.z + v.w * v.w;
        }
        dI[t] = s;
    } else if (t < 2 * TS) {
        const int r = t - TS;
        float s = 0.f;
        const int sw = (r >> 2) & 7;
        for (int c = 0; c < NCH; ++c) {
            float4 v = xj4[r * LDC + (c ^ sw)];
            s += v.x * v.x + v.y * v.y + v.z * v.z + v.w * v.w;
        }
        dJ[r] = s;
    }
    __syncthreads();

    const int ty = t >> 4, tx = t & 15;  // 16x16 threads, 4x4 reg tile each

    float acc[4][4] = {};
    #pragma unroll 5
    for (int k4 = 0; k4 < NCH; ++k4) {
        float4 a4[4], b4[4];
        #pragma unroll
        for (int m = 0; m < 4; ++m)
            a4[m] = xi4[(ty * 4 + m) * LDC + (k4 ^ (ty & 7))];
        #pragma unroll
        for (int n = 0; n < 4; ++n)
            b4[n] = xj4[(tx * 4 + n) * LDC + (k4 ^ (tx & 7))];
        #pragma unroll
        for (int m = 0; m < 4; ++m)
            #pragma unroll
            for (int n = 0; n < 4; ++n) {
                acc[m][n] += a4[m].x * b4[n].x;
                acc[m][n] += a4[m].y * b4[n].y;
                acc[m][n] += a4[m].z * b4[n].z;
                acc[m][n] += a4[m].w * b4[n].w;
            }
    }

    const float tt = expf(temp[0]);

    float vals[4][4];
    #pragma unroll
    for (int m = 0; m < 4; ++m) {
        const int gi = i0 + ty * 4 + m;
        const float di = dI[ty * 4 + m];
        #pragma unroll
        for (int n = 0; n < 4; ++n) {
            const int gj = j0 + tx * 4 + n;
            float u = di + dJ[tx * 4 + n] - 2.f * acc[m][n];
            u = fmaxf(u, 0.f);
            vals[m][n] = (gi == gj) ? sqrtf(EPS) : sqrtf(tt * u + EPS);
        }
    }

    // Row sums: reduce over tx (16 lanes) within the wave, one atomic per row.
    #pragma unroll
    for (int m = 0; m < 4; ++m) {
        float rs = vals[m][0] + vals[m][1] + vals[m][2] + vals[m][3];
        rs += __shfl_xor(rs, 1);
        rs += __shfl_xor(rs, 2);
        rs += __shfl_xor(rs, 4);
        rs += __shfl_xor(rs, 8);
        if (tx == 0) atomicAdd(&rowsum[b * DIM + i0 + ty * 4 + m], rs);
    }
    // Column sums (contribute to rowsum[j] via symmetry) -- only off-diagonal
    // tiles (diag tile's full-row sum already covers its columns).
    if (ti != tj) {
        #pragma unroll
        for (int n = 0; n < 4; ++n) {
            float cs = vals[0][n] + vals[1][n] + vals[2][n] + vals[3][n];
            cs += __shfl_xor(cs, 16);
            cs += __shfl_xor(cs, 32);
            if ((t & 48) == 0)  // wave-local ty == 0 lanes hold reduced value
                atomicAdd(&rowsum[b * DIM + j0 + tx * 4 + n], cs);
        }
    }

    // Packed upper-triangle writes: idx = b*TRI + gi*DIM - gi*(gi-1)/2 + (gj-gi)
    #pragma unroll
    for (int m = 0; m < 4; ++m) {
        const int gi = i0 + ty * 4 + m;
        const size_t rowbase = (size_t)b * TRI + (size_t)gi * DIM
                             - ((size_t)gi * (gi - 1)) / 2 - gi;
        #pragma unroll
        for (int n = 0; n < 4; ++n) {
            const int gj = j0 + tx * 4 + n;
            if (gj >= gi) out[rowbase + gj] = vals[m][n];
        }
    }
}

// Kernel C: per-batch row means + total mean.
__global__ __launch_bounds__(256) void means_kernel(
    const float* __restrict__ rowsum, float* __restrict__ rm,
    float* __restrict__ totm)
{
    const int b = blockIdx.x, t = threadIdx.x;
    float s = 0.f;
    for (int i = t; i < DIM; i += 256) {
        float v = rowsum[b * DIM + i];
        rm[b * DIM + i] = v * (1.0f / DIM);
        s += v;
    }
    s += __shfl_down(s, 32);
    s += __shfl_down(s, 16);
    s += __shfl_down(s, 8);
    s += __shfl_down(s, 4);
    s += __shfl_down(s, 2);
    s += __shfl_down(s, 1);
    __shared__ float red[4];
    if ((t & 63) == 0) red[t >> 6] = s;
    __syncthreads();
    if (t == 0)
        totm[b] = (red[0] + red[1] + red[2] + red[3])
                * (1.0f / ((float)DIM * (float)DIM));
}

// Kernel D: in-place double-centering of the packed triu output.
__global__ __launch_bounds__(256) void center_kernel(
    float* __restrict__ out, const float* __restrict__ rm,
    const float* __restrict__ totm)
{
    const int blk = blockIdx.x;
    const int b = blk / DIM, i = blk % DIM;
    const int L = DIM - i;
    const size_t base = (size_t)b * TRI + (size_t)i * DIM
                      - ((size_t)i * (i - 1)) / 2;
    const float c = totm[b] - rm[b * DIM + i];
    const float* rmj = rm + b * DIM + i;
    for (int off = threadIdx.x; off < L; off += 256) {
        out[base + off] += c - rmj[off];
    }
}

extern "C" void kernel_launch(void* const* d_in, const int* in_sizes, int n_in,
                              void* d_out, int out_size, void* d_ws, size_t ws_size,
                              hipStream_t stream)
{
    const float* x    = (const float*)d_in[0];
    const float* temp = (const float*)d_in[1];
    float* out    = (float*)d_out;
    float* rowsum = (float*)d_ws;              // [B_*DIM]
    float* rm     = rowsum + B_ * DIM;         // [B_*DIM]
    float* totm   = rm + B_ * DIM;             // [B_]

    hipMemsetAsync(rowsum, 0, B_ * DIM * sizeof(float), stream);
    dcov_tile_kernel<<<B_ * NTP, 256, 0, stream>>>(x, temp, out, rowsum);
    means_kernel<<<B_, 256, 0, stream>>>(rowsum, rm, totm);
    center_kernel<<<B_ * DIM, 256, 0, stream>>>(out, rm, totm);
}

// Round 2
// 102.796 us; speedup vs baseline: 1.4314x; 1.4314x over previous
//
#include <hip/hip_runtime.h>
#include <hip/hip_bf16.h>

#define B_   64
#define DIM  640
#define NPIX 100
#define TS   64      // tile size
#define NT   10      // DIM / TS
#define NTP  55      // NT*(NT+1)/2 triu tile pairs
#define TRI  205120  // DIM*(DIM+1)/2
#define EPS  1e-5f
#define KCH  16      // 16B chunks per LDS row (row stride = 128 bf16 = 256B)
#define NKC  13      // data chunks per row (k 0..103; k>=100 zeroed)
#define F4PR 25      // float4 per source row (100 floats)

typedef __attribute__((ext_vector_type(8)))  short bf16x8;
typedef __attribute__((ext_vector_type(16))) float f32x16;

__device__ inline unsigned pk_bf16(float a, float b) {
    __hip_bfloat162 h = __float22bfloat162_rn(float2{a, b});  // x = low half
    return *reinterpret_cast<unsigned*>(&h);
}
__device__ inline float bf2f(unsigned s) {
    union { unsigned u; float f; } v; v.u = s << 16; return v.f;
}

// Stage one 64x100 fp32 tile -> bf16 LDS tile, XOR-swizzled 16B chunks,
// K zero-padded to 112 (7 MFMA k-steps of 16).
__device__ inline void stage_tile(const float4* __restrict__ src,
                                  uint4* dst, int t) {
    for (int f = t; f < TS * NKC; f += 256) {
        int r = f / NKC, c = f - r * NKC;
        const float4* s = src + (size_t)r * F4PR + 2 * c;
        float4 lo = s[0];
        float4 hi = make_float4(0.f, 0.f, 0.f, 0.f);
        if (c < 12) hi = s[1];                       // c==12: k 100..103 -> 0
        uint4 p;
        p.x = pk_bf16(lo.x, lo.y);
        p.y = pk_bf16(lo.z, lo.w);
        p.z = pk_bf16(hi.x, hi.y);
        p.w = pk_bf16(hi.z, hi.w);
        dst[r * KCH + (c ^ (r & 7))] = p;
    }
    for (int r = t; r < TS; r += 256) {              // zero pad chunk 13
        uint4 z = {0u, 0u, 0u, 0u};
        dst[r * KCH + (13 ^ (r & 7))] = z;
    }
}

// Sum of squares of one LDS row (gram diagonal), from the bf16 values so it
// is consistent with the MFMA gram (dcov diagonal cancels to ~0 -> clipped).
__device__ inline float rowsq(const uint4* tile, int r) {
    float s = 0.f;
    for (int c = 0; c < NKC; ++c) {
        uint4 p = tile[r * KCH + (c ^ (r & 7))];
        unsigned w[4] = {p.x, p.y, p.z, p.w};
        #pragma unroll
        for (int q = 0; q < 4; ++q) {
            float a = bf2f(w[q] & 0xffffu), b = bf2f(w[q] >> 16);
            s += a * a + b * b;
        }
    }
    return s;
}

// 64x64 gram tile via 4 waves x (32x32 quadrant), K=112 (7 MFMA steps).
__device__ inline f32x16 gram_tile(const uint4* xi, const uint4* xj,
                                   int t, int wm, int wn) {
    const int lane = t & 63;
    const int arow = wm * 32 + (lane & 31);
    const int brow = wn * 32 + (lane & 31);
    const int khalf = lane >> 5;
    f32x16 acc = {};
    #pragma unroll
    for (int kk = 0; kk < 7; ++kk) {
        int c = kk * 2 + khalf;
        bf16x8 a = *reinterpret_cast<const bf16x8*>(&xi[arow * KCH + (c ^ (arow & 7))]);
        bf16x8 bb = *reinterpret_cast<const bf16x8*>(&xj[brow * KCH + (c ^ (brow & 7))]);
        acc = __builtin_amdgcn_mfma_f32_32x32x16_bf16(a, bb, acc, 0, 0, 0);
    }
    return acc;
}

__device__ inline void decode_tp(int tp, int& ti, int& tj) {
    ti = 0;
    while (tp >= NT - ti) { tp -= NT - ti; ++ti; }
    tj = ti + tp;
}

// Pass A: per (b, triu tile pair) accumulate dcov row sums (symmetric tile
// contributes rows i via row sums and rows j via col sums).
__global__ __launch_bounds__(256, 4) void rowsum_kernel(
    const float* __restrict__ x, const float* __restrict__ temp,
    float* __restrict__ rowsum)
{
    __shared__ uint4 xi[TS * KCH], xj[TS * KCH];
    __shared__ float dI[TS], dJ[TS], rpart[TS], cpart[TS];

    const int t = threadIdx.x;
    const int b = blockIdx.x / NTP;
    int ti, tj; decode_tp(blockIdx.x % NTP, ti, tj);
    const int i0 = ti * TS, j0 = tj * TS;

    const float4* xb4 = reinterpret_cast<const float4*>(x) + (size_t)b * DIM * F4PR;
    stage_tile(xb4 + (size_t)i0 * F4PR, xi, t);
    stage_tile(xb4 + (size_t)j0 * F4PR, xj, t);
    const float tt = expf(temp[0]);
    __syncthreads();

    if (t < TS) dI[t] = rowsq(xi, t);
    else if (t < 2 * TS) dJ[t - TS] = rowsq(xj, t - TS);
    else if (t < 3 * TS) rpart[t - 2 * TS] = 0.f;
    else cpart[t - 3 * TS] = 0.f;
    __syncthreads();

    const int wv = t >> 6, lane = t & 63;
    const int wm = wv >> 1, wn = wv & 1;
    f32x16 acc = gram_tile(xi, xj, t, wm, wn);

    const int khalf = lane >> 5;
    const int col_l = wn * 32 + (lane & 31);
    const float SQEPS = 3.1622776601683794e-3f;  // sqrt(1e-5)
    float colacc = 0.f;
    #pragma unroll
    for (int r = 0; r < 16; ++r) {
        int row_l = wm * 32 + (r & 3) + 8 * (r >> 2) + 4 * khalf;
        int gi = i0 + row_l, gj = j0 + col_l;
        float u = dI[row_l] + dJ[col_l] - 2.f * acc[r];
        float v = (gi == gj) ? SQEPS : sqrtf(tt * fmaxf(u, 0.f) + EPS);
        float rs = v;
        rs += __shfl_xor(rs, 1);  rs += __shfl_xor(rs, 2);
        rs += __shfl_xor(rs, 4);  rs += __shfl_xor(rs, 8);
        rs += __shfl_xor(rs, 16);
        if ((lane & 31) == 0) atomicAdd(&rpart[row_l], rs);
        colacc += v;
    }
    colacc += __shfl_xor(colacc, 32);
    if (lane < 32) atomicAdd(&cpart[col_l], colacc);
    __syncthreads();

    if (t < TS) atomicAdd(&rowsum[b * DIM + i0 + t], rpart[t]);
    else if (t < 2 * TS && ti != tj)
        atomicAdd(&rowsum[b * DIM + j0 + (t - TS)], cpart[t - TS]);
}

// Row means + total mean per batch.
__global__ __launch_bounds__(256) void means_kernel(
    const float* __restrict__ rowsum, float* __restrict__ rm,
    float* __restrict__ totm)
{
    const int b = blockIdx.x, t = threadIdx.x;
    float s = 0.f;
    for (int i = t; i < DIM; i += 256) {
        float v = rowsum[b * DIM + i];
        rm[b * DIM + i] = v * (1.0f / DIM);
        s += v;
    }
    s += __shfl_down(s, 32); s += __shfl_down(s, 16); s += __shfl_down(s, 8);
    s += __shfl_down(s, 4);  s += __shfl_down(s, 2);  s += __shfl_down(s, 1);
    __shared__ float red[4];
    if ((t & 63) == 0) red[t >> 6] = s;
    __syncthreads();
    if (t == 0)
        totm[b] = (red[0] + red[1] + red[2] + red[3])
                * (1.0f / ((float)DIM * (float)DIM));
}

// Pass B: recompute each triu tile, apply centering, write packed triu.
__global__ __launch_bounds__(256, 4) void write_kernel(
    const float* __restrict__ x, const float* __restrict__ temp,
    const float* __restrict__ rm, const float* __restrict__ totm,
    float* __restrict__ out)
{
    __shared__ uint4 xi[TS * KCH], xj[TS * KCH];
    __shared__ float dI[TS], dJ[TS], rmI[TS], rmJ[TS];

    const int t = threadIdx.x;
    const int b = blockIdx.x / NTP;
    int ti, tj; decode_tp(blockIdx.x % NTP, ti, tj);
    const int i0 = ti * TS, j0 = tj * TS;

    const float4* xb4 = reinterpret_cast<const float4*>(x) + (size_t)b * DIM * F4PR;
    stage_tile(xb4 + (size_t)i0 * F4PR, xi, t);
    stage_tile(xb4 + (size_t)j0 * F4PR, xj, t);
    const float tt = expf(temp[0]);
    const float tm = totm[b];
    __syncthreads();

    if (t < TS) dI[t] = rowsq(xi, t);
    else if (t < 2 * TS) dJ[t - TS] = rowsq(xj, t - TS);
    else if (t < 3 * TS) rmI[t - 2 * TS] = rm[b * DIM + i0 + (t - 2 * TS)];
    else rmJ[t - 3 * TS] = rm[b * DIM + j0 + (t - 3 * TS)];
    __syncthreads();

    const int wv = t >> 6, lane = t & 63;
    const int wm = wv >> 1, wn = wv & 1;
    f32x16 acc = gram_tile(xi, xj, t, wm, wn);

    const int khalf = lane >> 5;
    const int col_l = wn * 32 + (lane & 31);
    const float SQEPS = 3.1622776601683794e-3f;
    #pragma unroll
    for (int r = 0; r < 16; ++r) {
        int row_l = wm * 32 + (r & 3) + 8 * (r >> 2) + 4 * khalf;
        int gi = i0 + row_l, gj = j0 + col_l;
        float u = dI[row_l] + dJ[col_l] - 2.f * acc[r];
        float v = (gi == gj) ? SQEPS : sqrtf(tt * fmaxf(u, 0.f) + EPS);
        float cv = v - rmI[row_l] - rmJ[col_l] + tm;
        if (gj >= gi) {
            size_t idx = (size_t)b * TRI + (size_t)gi * DIM
                       - ((size_t)gi * (gi - 1)) / 2 - gi + gj;
            out[idx] = cv;
        }
    }
}

extern "C" void kernel_launch(void* const* d_in, const int* in_sizes, int n_in,
                              void* d_out, int out_size, void* d_ws, size_t ws_size,
                              hipStream_t stream)
{
    const float* x    = (const float*)d_in[0];
    const float* temp = (const float*)d_in[1];
    float* out    = (float*)d_out;
    float* rowsum = (float*)d_ws;              // [B_*DIM]
    float* rm     = rowsum + B_ * DIM;         // [B_*DIM]
    float* totm   = rm + B_ * DIM;             // [B_]

    hipMemsetAsync(rowsum, 0, B_ * DIM * sizeof(float), stream);
    rowsum_kernel<<<B_ * NTP, 256, 0, stream>>>(x, temp, rowsum);
    means_kernel<<<B_, 256, 0, stream>>>(rowsum, rm, totm);
    write_kernel<<<B_ * NTP, 256, 0, stream>>>(x, temp, rm, totm, out);
}

// Round 3
// 60.337 us; speedup vs baseline: 2.4386x; 1.7037x over previous
//
#include <hip/hip_runtime.h>
#include <hip/hip_bf16.h>

#define B_    64
#define DIM   640
#define NPIX  100
#define TS    64
#define NT    10        // DIM/TS
#define NTP   55        // triu tile pairs
#define TRI   205120    // DIM*(DIM+1)/2
#define EPS   1e-5f
#define SQEPS 3.1622776601683794e-3f
#define KCH   16        // uint4 chunks per image row (256 B row stride)
#define TILE_U4 1024    // uint4 per 64-row tile image (16 KB)

typedef __attribute__((ext_vector_type(8)))  short bf16x8;
typedef __attribute__((ext_vector_type(16))) float f32x16;

__device__ inline unsigned pk_bf16(float a, float b) {
    __hip_bfloat162 h = __float22bfloat162_rn(float2{a, b});
    return *reinterpret_cast<unsigned*>(&h);
}
__device__ inline float bfr(float x) {
    return __bfloat162float(__float2bfloat16(x));
}
__device__ inline void gload_lds16(const void* g, void* l) {
    __builtin_amdgcn_global_load_lds(
        (const __attribute__((address_space(1))) unsigned*)g,
        (__attribute__((address_space(3))) unsigned*)l, 16, 0, 0);
}

// ---------------------------------------------------------------------------
// Prep: per (b,ti) write bf16 tile image (pre-swizzled, zero-padded K->128)
// and per-row sum of squares of the bf16-rounded values; zero rowsum.
// ---------------------------------------------------------------------------
__global__ __launch_bounds__(256) void prep_kernel(
    const float* __restrict__ x, uint4* __restrict__ img,
    float* __restrict__ dsq, float* __restrict__ rowsum)
{
    const int blk = blockIdx.x;                 // b*NT + ti
    const int b = blk / NT, ti = blk % NT;
    const int t = threadIdx.x;
    const float4* src = (const float4*)x + (size_t)(b * DIM + ti * TS) * 25;
    uint4* dst = img + (size_t)blk * TILE_U4;

    for (int f = t; f < TS * KCH; f += 256) {
        int r = f >> 4, c = f & 15;
        uint4 p = {0u, 0u, 0u, 0u};
        if (c <= 12) {
            float4 lo = src[(size_t)r * 25 + 2 * c];
            float4 hi = make_float4(0.f, 0.f, 0.f, 0.f);
            if (c < 12) hi = src[(size_t)r * 25 + 2 * c + 1];
            p.x = pk_bf16(lo.x, lo.y);
            p.y = pk_bf16(lo.z, lo.w);
            p.z = pk_bf16(hi.x, hi.y);
            p.w = pk_bf16(hi.z, hi.w);
        }
        dst[r * KCH + (c ^ (r & 7))] = p;
    }

    // sum of squares: 4 threads per row
    const int r = t >> 2, q = t & 3;
    float s = 0.f;
    for (int j = q; j < 25; j += 4) {
        float4 v = src[(size_t)r * 25 + j];
        float a0 = bfr(v.x), a1 = bfr(v.y), a2 = bfr(v.z), a3 = bfr(v.w);
        s += a0 * a0 + a1 * a1 + a2 * a2 + a3 * a3;
    }
    s += __shfl_xor(s, 1);
    s += __shfl_xor(s, 2);
    if (q == 0) dsq[b * DIM + ti * TS + r] = s;
    if (t < TS) rowsum[b * DIM + ti * TS + t] = 0.f;
}

// XCD-grouped block id -> (b, ti, tj).  3520 % 8 == 0 -> bijective.
__device__ inline void decode_blk(int raw, int& b, int& ti, int& tj) {
    int bid = (raw & 7) * (B_ * NTP / 8) + (raw >> 3);
    b = bid / NTP;
    int tp = bid % NTP;
    int i = 0;
    while (tp >= NT - i) { tp -= NT - i; ++i; }
    ti = i; tj = i + tp;
}

__device__ inline void stage_pair(const uint4* __restrict__ img, int b,
                                  int ti, int tj, uint4* xs, int wv, int lane) {
    const char* gi = (const char*)(img + (size_t)(b * NT + ti) * TILE_U4);
    const char* gj = (const char*)(img + (size_t)(b * NT + tj) * TILE_U4);
    char* lb = (char*)xs;
    #pragma unroll
    for (int it = 0; it < 8; ++it) {
        int seg = (wv * 8 + it) * 1024;
        const char* g = (seg < 16384) ? (gi + seg) : (gj + seg - 16384);
        gload_lds16(g + lane * 16, lb + seg);
    }
}

// ---------------------------------------------------------------------------
// Pass A: dcov row sums.  Dual MFMA (tile and tile^T) makes both the row- and
// col-sum of the sqrt-transformed tile lane-local.
// ---------------------------------------------------------------------------
__global__ __launch_bounds__(256, 4) void rowsum_kernel(
    const uint4* __restrict__ img, const float* __restrict__ dsq,
    const float* __restrict__ temp, float* __restrict__ rowsum)
{
    __shared__ uint4 xs[2 * TILE_U4];
    __shared__ float dI[TS], dJ[TS], rpart[TS], cpart[TS];

    int b, ti, tj; decode_blk(blockIdx.x, b, ti, tj);
    const int t = threadIdx.x, wv = t >> 6, lane = t & 63;
    const int i0 = ti * TS, j0 = tj * TS;

    stage_pair(img, b, ti, tj, xs, wv, lane);
    if (t < TS)            { dI[t] = dsq[b * DIM + i0 + t];        rpart[t] = 0.f; }
    else if (t < 2 * TS)   { dJ[t - TS] = dsq[b * DIM + j0 + t - TS]; cpart[t - TS] = 0.f; }
    const float tt = expf(temp[0]);
    __syncthreads();

    const uint4* xi = xs;
    const uint4* xj = xs + TILE_U4;
    const int wm = wv >> 1, wn = wv & 1;
    const int khalf = lane >> 5, l31 = lane & 31;
    const int arow = wm * 32 + l31, brow = wn * 32 + l31;

    f32x16 acc = {}, accT = {};
    #pragma unroll
    for (int kk = 0; kk < 7; ++kk) {
        int c = kk * 2 + khalf;
        bf16x8 a  = *(const bf16x8*)&xi[arow * KCH + (c ^ (arow & 7))];
        bf16x8 bb = *(const bf16x8*)&xj[brow * KCH + (c ^ (brow & 7))];
        acc  = __builtin_amdgcn_mfma_f32_32x32x16_bf16(a, bb, acc, 0, 0, 0);
        accT = __builtin_amdgcn_mfma_f32_32x32x16_bf16(bb, a, accT, 0, 0, 0);
    }

    const float dJc = dJ[wn * 32 + l31];   // acc path: col j fixed per lane
    const float dIc = dI[wm * 32 + l31];   // accT path: col i fixed per lane
    const bool dg = (ti == tj);
    float csum = 0.f, rsum = 0.f;
    #pragma unroll
    for (int r = 0; r < 16; ++r) {
        int rf = (r & 3) + 8 * (r >> 2) + 4 * khalf;
        int row_l  = wm * 32 + rf;   // i index of acc rows
        int rowT_l = wn * 32 + rf;   // j index of accT rows
        float u = dI[row_l] + dJc - 2.f * acc[r];
        float v = (dg && row_l == wn * 32 + l31)
                ? SQEPS : sqrtf(tt * fmaxf(u, 0.f) + EPS);
        csum += v;
        float uT = dIc + dJ[rowT_l] - 2.f * accT[r];
        float vT = (dg && rowT_l == wm * 32 + l31)
                 ? SQEPS : sqrtf(tt * fmaxf(uT, 0.f) + EPS);
        rsum += vT;
    }
    csum += __shfl_xor(csum, 32);
    rsum += __shfl_xor(rsum, 32);
    if (lane < 32) {
        atomicAdd(&cpart[wn * 32 + lane], csum);
        atomicAdd(&rpart[wm * 32 + lane], rsum);
    }
    __syncthreads();

    if (t < TS) atomicAdd(&rowsum[b * DIM + i0 + t], rpart[t]);
    else if (t < 2 * TS && ti != tj)
        atomicAdd(&rowsum[b * DIM + j0 + (t - TS)], cpart[t - TS]);
}

// ---------------------------------------------------------------------------
// Row means + total mean per batch.
// ---------------------------------------------------------------------------
__global__ __launch_bounds__(256) void means_kernel(
    const float* __restrict__ rowsum, float* __restrict__ rm,
    float* __restrict__ totm)
{
    const int b = blockIdx.x, t = threadIdx.x;
    float s = 0.f;
    for (int i = t; i < DIM; i += 256) {
        float v = rowsum[b * DIM + i];
        rm[b * DIM + i] = v * (1.0f / DIM);
        s += v;
    }
    s += __shfl_down(s, 32); s += __shfl_down(s, 16); s += __shfl_down(s, 8);
    s += __shfl_down(s, 4);  s += __shfl_down(s, 2);  s += __shfl_down(s, 1);
    __shared__ float red[4];
    if ((t & 63) == 0) red[t >> 6] = s;
    __syncthreads();
    if (t == 0)
        totm[b] = (red[0] + red[1] + red[2] + red[3])
                * (1.0f / ((float)DIM * (float)DIM));
}

// ---------------------------------------------------------------------------
// Pass B: recompute tile, center, write packed triu.
// ---------------------------------------------------------------------------
__global__ __launch_bounds__(256, 4) void write_kernel(
    const uint4* __restrict__ img, const float* __restrict__ dsq,
    const float* __restrict__ temp, const float* __restrict__ rm,
    const float* __restrict__ totm, float* __restrict__ out)
{
    __shared__ uint4 xs[2 * TILE_U4];
    __shared__ float dI[TS], dJ[TS], rmI[TS], rmJ[TS];

    int b, ti, tj; decode_blk(blockIdx.x, b, ti, tj);
    const int t = threadIdx.x, wv = t >> 6, lane = t & 63;
    const int i0 = ti * TS, j0 = tj * TS;

    stage_pair(img, b, ti, tj, xs, wv, lane);
    if      (t < TS)     dI[t]        = dsq[b * DIM + i0 + t];
    else if (t < 2*TS)   dJ[t - TS]   = dsq[b * DIM + j0 + (t - TS)];
    else if (t < 3*TS)   rmI[t - 2*TS] = rm[b * DIM + i0 + (t - 2*TS)];
    else                 rmJ[t - 3*TS] = rm[b * DIM + j0 + (t - 3*TS)];
    const float tt = expf(temp[0]);
    const float tm = totm[b];
    __syncthreads();

    const uint4* xi = xs;
    const uint4* xj = xs + TILE_U4;
    const int wm = wv >> 1, wn = wv & 1;
    const int khalf = lane >> 5, l31 = lane & 31;
    const int arow = wm * 32 + l31, brow = wn * 32 + l31;

    f32x16 acc = {};
    #pragma unroll
    for (int kk = 0; kk < 7; ++kk) {
        int c = kk * 2 + khalf;
        bf16x8 a  = *(const bf16x8*)&xi[arow * KCH + (c ^ (arow & 7))];
        bf16x8 bb = *(const bf16x8*)&xj[brow * KCH + (c ^ (brow & 7))];
        acc = __builtin_amdgcn_mfma_f32_32x32x16_bf16(a, bb, acc, 0, 0, 0);
    }

    const int col_l = wn * 32 + l31;
    const int gj = j0 + col_l;
    const float dJc = dJ[col_l], rmJc = rmJ[col_l];
    #pragma unroll
    for (int r = 0; r < 16; ++r) {
        int rf = (r & 3) + 8 * (r >> 2) + 4 * khalf;
        int row_l = wm * 32 + rf;
        int gi = i0 + row_l;
        float u = dI[row_l] + dJc - 2.f * acc[r];
        float v = (gi == gj) ? SQEPS : sqrtf(tt * fmaxf(u, 0.f) + EPS);
        float cv = v - rmI[row_l] - rmJc + tm;
        if (gj >= gi) {
            size_t idx = (size_t)b * TRI + (size_t)gi * DIM
                       - ((size_t)gi * (gi - 1)) / 2 - gi + gj;
            out[idx] = cv;
        }
    }
}

extern "C" void kernel_launch(void* const* d_in, const int* in_sizes, int n_in,
                              void* d_out, int out_size, void* d_ws, size_t ws_size,
                              hipStream_t stream)
{
    const float* x    = (const float*)d_in[0];
    const float* temp = (const float*)d_in[1];
    float* out    = (float*)d_out;

    float* rowsum = (float*)d_ws;               // [B_*DIM]
    float* rm     = rowsum + B_ * DIM;          // [B_*DIM]
    float* totm   = rm + B_ * DIM;              // [64]
    float* dsq    = totm + 64;                  // [B_*DIM]
    uint4* img    = (uint4*)(dsq + B_ * DIM);   // [B_*NT*TILE_U4] = 10.5 MB

    prep_kernel  <<<B_ * NT,  256, 0, stream>>>(x, img, dsq, rowsum);
    rowsum_kernel<<<B_ * NTP, 256, 0, stream>>>(img, dsq, temp, rowsum);
    means_kernel <<<B_,       256, 0, stream>>>(rowsum, rm, totm);
    write_kernel <<<B_ * NTP, 256, 0, stream>>>(img, dsq, temp, rm, totm, out);
}

// Round 4
// 59.959 us; speedup vs baseline: 2.4540x; 1.0063x over previous
//
#include <hip/hip_runtime.h>
#include <hip/hip_bf16.h>

#define B_    64
#define DIM   640
#define TS    64
#define NT    10        // DIM/TS
#define NTP   55        // triu tile pairs
#define TRI   205120    // DIM*(DIM+1)/2
#define EPS   1e-5f
#define SQEPS 3.1622776601683794e-3f
#define KCH   16        // uint4 chunks per image row (256 B row stride)
#define TILE_U4 1024    // uint4 per 64-row tile image (16 KB)
#define TILE_B  16384

typedef __attribute__((ext_vector_type(8)))  short bf16x8;
typedef __attribute__((ext_vector_type(16))) float f32x16;

__device__ inline unsigned pk_bf16(float a, float b) {
    __hip_bfloat162 h = __float22bfloat162_rn(float2{a, b});
    return *reinterpret_cast<unsigned*>(&h);
}
__device__ inline float bfr(float x) {
    return __bfloat162float(__float2bfloat16(x));
}
__device__ inline void gload_lds16(const void* g, void* l) {
    __builtin_amdgcn_global_load_lds(
        (const __attribute__((address_space(1))) unsigned*)g,
        (__attribute__((address_space(3))) unsigned*)l, 16, 0, 0);
}

// ---------------------------------------------------------------------------
// Prep: per (b,ti) write bf16 tile image (chunk-XOR-swizzled, K zero-padded
// to 128) + per-row sum of squares of bf16-rounded values; zero totm.
// ---------------------------------------------------------------------------
__global__ __launch_bounds__(256) void prep_kernel(
    const float* __restrict__ x, uint4* __restrict__ img,
    float* __restrict__ dsq, float* __restrict__ totm)
{
    const int blk = blockIdx.x;                 // b*NT + ti
    const int b = blk / NT, ti = blk % NT;
    const int t = threadIdx.x;
    const float4* src = (const float4*)x + (size_t)(b * DIM + ti * TS) * 25;
    uint4* dst = img + (size_t)blk * TILE_U4;

    for (int f = t; f < TS * KCH; f += 256) {
        int r = f >> 4, c = f & 15;
        uint4 p = {0u, 0u, 0u, 0u};
        if (c <= 12) {
            float4 lo = src[(size_t)r * 25 + 2 * c];
            float4 hi = make_float4(0.f, 0.f, 0.f, 0.f);
            if (c < 12) hi = src[(size_t)r * 25 + 2 * c + 1];
            p.x = pk_bf16(lo.x, lo.y);
            p.y = pk_bf16(lo.z, lo.w);
            p.z = pk_bf16(hi.x, hi.y);
            p.w = pk_bf16(hi.z, hi.w);
        }
        dst[r * KCH + (c ^ (r & 15))] = p;
    }

    // per-row sum of squares: 4 threads per row
    const int r = t >> 2, q = t & 3;
    float s = 0.f;
    for (int j = q; j < 25; j += 4) {
        float4 v = src[(size_t)r * 25 + j];
        float a0 = bfr(v.x), a1 = bfr(v.y), a2 = bfr(v.z), a3 = bfr(v.w);
        s += a0 * a0 + a1 * a1 + a2 * a2 + a3 * a3;
    }
    s += __shfl_xor(s, 1);
    s += __shfl_xor(s, 2);
    if (q == 0) dsq[b * DIM + ti * TS + r] = s;
    if (ti == 0 && t == 0) totm[b] = 0.f;
}

__device__ inline void stage_tile16(const char* __restrict__ gt, char* lt,
                                    int wv, int lane) {
    #pragma unroll
    for (int it = 0; it < 4; ++it) {
        const int seg = (wv * 4 + it) * 1024;
        gload_lds16(gt + seg + lane * 16, lt + seg);
    }
}

// ---------------------------------------------------------------------------
// Pass A: one block per (b, strip ti).  Computes dcov rows [i0, i0+64) vs all
// j, accumulating row sums fully in-block (no global atomics).  Strip-i MFMA
// fragments live in registers; j tiles double-buffered via global_load_lds.
// ---------------------------------------------------------------------------
__global__ __launch_bounds__(256, 4) void strip_kernel(
    const uint4* __restrict__ img, const float* __restrict__ dsq,
    const float* __restrict__ temp, float* __restrict__ rowsum,
    float* __restrict__ totm)
{
    __shared__ uint4 xj[2][TILE_U4];
    __shared__ float dAll[DIM];
    __shared__ float rpart[TS];

    const int raw = blockIdx.x;                     // 640 blocks, 640%8==0
    const int bid = (raw & 7) * (B_ * NT / 8) + (raw >> 3);
    const int b = bid / NT, ti = bid % NT;
    const int t = threadIdx.x, wv = t >> 6, lane = t & 63;
    const int iq = wv & 1, jq = wv >> 1;
    const int l31 = lane & 31, khalf = lane >> 5;

    const char* base = (const char*)(img + (size_t)b * NT * TILE_U4);

    stage_tile16(base, (char*)xj[0], wv, lane);     // j-tile 0

    for (int i = t; i < DIM; i += 256) dAll[i] = dsq[b * DIM + i];
    if (t < TS) rpart[t] = 0.f;

    // strip-i B-operand fragments -> registers (direct global reads, L2-hit)
    const int irow = iq * 32 + l31;
    bf16x8 bfrag[7];
    #pragma unroll
    for (int kk = 0; kk < 7; ++kk) {
        int c = kk * 2 + khalf;
        bfrag[kk] = *(const bf16x8*)(base + (size_t)ti * TILE_B
                     + irow * 256 + ((c ^ (irow & 15)) * 16));
    }
    const float tt = expf(temp[0]);
    __syncthreads();

    const float dIc = dAll[ti * TS + irow];
    float rsum = 0.f;
    for (int jt = 0; jt < NT; ++jt) {
        const uint4* buf = xj[jt & 1];
        if (jt + 1 < NT)
            stage_tile16(base + (size_t)(jt + 1) * TILE_B,
                         (char*)xj[(jt + 1) & 1], wv, lane);
        f32x16 acc = {};
        const int jrow_a = jq * 32 + l31;
        #pragma unroll
        for (int kk = 0; kk < 7; ++kk) {
            int c = kk * 2 + khalf;
            bf16x8 a = *(const bf16x8*)&buf[jrow_a * KCH + (c ^ (jrow_a & 15))];
            acc = __builtin_amdgcn_mfma_f32_32x32x16_bf16(a, bfrag[kk], acc, 0, 0, 0);
        }
        const bool dg = (jt == ti);
        #pragma unroll
        for (int r = 0; r < 16; ++r) {
            int rf = (r & 3) + 8 * (r >> 2) + 4 * khalf;
            int jrow = jq * 32 + rf;
            float u = dAll[jt * TS + jrow] + dIc - 2.f * acc[r];
            float v = (dg && jrow == irow) ? SQEPS
                                           : sqrtf(tt * fmaxf(u, 0.f) + EPS);
            rsum += v;
        }
        __syncthreads();   // next j buffer staged; guards buffer reuse
    }

    rsum += __shfl_xor(rsum, 32);
    if (lane < 32) atomicAdd(&rpart[iq * 32 + lane], rsum);
    __syncthreads();

    if (t < TS) {
        float rv = rpart[t];
        rowsum[b * DIM + ti * TS + t] = rv;
        float s = rv;
        s += __shfl_xor(s, 1);  s += __shfl_xor(s, 2);  s += __shfl_xor(s, 4);
        s += __shfl_xor(s, 8);  s += __shfl_xor(s, 16); s += __shfl_xor(s, 32);
        if (t == 0)
            atomicAdd(&totm[b], s * (1.0f / ((float)DIM * (float)DIM)));
    }
}

// XCD-grouped block id -> (b, ti, tj).  3520 % 8 == 0 -> bijective.
__device__ inline void decode_blk(int raw, int& b, int& ti, int& tj) {
    int bid = (raw & 7) * (B_ * NTP / 8) + (raw >> 3);
    b = bid / NTP;
    int tp = bid % NTP;
    int i = 0;
    while (tp >= NT - i) { tp -= NT - i; ++i; }
    ti = i; tj = i + tp;
}

__device__ inline void stage_pair(const uint4* __restrict__ img, int b,
                                  int ti, int tj, uint4* xs, int wv, int lane) {
    const char* gi = (const char*)(img + (size_t)(b * NT + ti) * TILE_U4);
    const char* gj = (const char*)(img + (size_t)(b * NT + tj) * TILE_U4);
    char* lb = (char*)xs;
    #pragma unroll
    for (int it = 0; it < 8; ++it) {
        int seg = (wv * 8 + it) * 1024;
        const char* g = (seg < TILE_B) ? (gi + seg) : (gj + seg - TILE_B);
        gload_lds16(g + lane * 16, lb + seg);
    }
}

// ---------------------------------------------------------------------------
// Pass B: recompute tile, center (rm/tm read inline), write packed triu.
// ---------------------------------------------------------------------------
__global__ __launch_bounds__(256, 4) void write_kernel(
    const uint4* __restrict__ img, const float* __restrict__ dsq,
    const float* __restrict__ temp, const float* __restrict__ rowsum,
    const float* __restrict__ totm, float* __restrict__ out)
{
    __shared__ uint4 xs[2 * TILE_U4];
    __shared__ float dI[TS], dJ[TS], rmI[TS], rmJ[TS];
    __shared__ float tms;

    int b, ti, tj; decode_blk(blockIdx.x, b, ti, tj);
    const int t = threadIdx.x, wv = t >> 6, lane = t & 63;
    const int i0 = ti * TS, j0 = tj * TS;

    stage_pair(img, b, ti, tj, xs, wv, lane);
    const float invD = 1.0f / (float)DIM;
    if (t < TS) {
        dI[t]  = dsq[b * DIM + i0 + t];
        rmI[t] = rowsum[b * DIM + i0 + t] * invD;
    } else if (t < 2 * TS) {
        dJ[t - TS]  = dsq[b * DIM + j0 + (t - TS)];
        rmJ[t - TS] = rowsum[b * DIM + j0 + (t - TS)] * invD;
    }
    if (t == 0) tms = totm[b];
    const float tt = expf(temp[0]);
    __syncthreads();

    const uint4* xi = xs;
    const uint4* xjt = xs + TILE_U4;
    const int wm = wv >> 1, wn = wv & 1;
    const int khalf = lane >> 5, l31 = lane & 31;
    const int arow = wm * 32 + l31, brow = wn * 32 + l31;

    f32x16 acc = {};
    #pragma unroll
    for (int kk = 0; kk < 7; ++kk) {
        int c = kk * 2 + khalf;
        bf16x8 a  = *(const bf16x8*)&xi[arow * KCH + (c ^ (arow & 15))];
        bf16x8 bb = *(const bf16x8*)&xjt[brow * KCH + (c ^ (brow & 15))];
        acc = __builtin_amdgcn_mfma_f32_32x32x16_bf16(a, bb, acc, 0, 0, 0);
    }

    const int col_l = wn * 32 + l31;
    const int gj = j0 + col_l;
    const float dJc = dJ[col_l], rmJc = rmJ[col_l];
    const float tm = tms;
    #pragma unroll
    for (int r = 0; r < 16; ++r) {
        int rf = (r & 3) + 8 * (r >> 2) + 4 * khalf;
        int row_l = wm * 32 + rf;
        int gi = i0 + row_l;
        float u = dI[row_l] + dJc - 2.f * acc[r];
        float v = (gi == gj) ? SQEPS : sqrtf(tt * fmaxf(u, 0.f) + EPS);
        float cv = v - rmI[row_l] - rmJc + tm;
        if (gj >= gi) {
            size_t idx = (size_t)b * TRI + (size_t)gi * DIM
                       - ((size_t)gi * (gi - 1)) / 2 - gi + gj;
            out[idx] = cv;
        }
    }
}

extern "C" void kernel_launch(void* const* d_in, const int* in_sizes, int n_in,
                              void* d_out, int out_size, void* d_ws, size_t ws_size,
                              hipStream_t stream)
{
    const float* x    = (const float*)d_in[0];
    const float* temp = (const float*)d_in[1];
    float* out    = (float*)d_out;

    float* rowsum = (float*)d_ws;               // [B_*DIM]
    float* totm   = rowsum + B_ * DIM;          // [64]
    float* dsq    = totm + 64;                  // [B_*DIM]
    uint4* img    = (uint4*)(dsq + B_ * DIM);   // [B_*NT*TILE_U4] = 10.5 MB

    prep_kernel <<<B_ * NT,  256, 0, stream>>>(x, img, dsq, totm);
    strip_kernel<<<B_ * NT,  256, 0, stream>>>(img, dsq, temp, rowsum, totm);
    write_kernel<<<B_ * NTP, 256, 0, stream>>>(img, dsq, temp, rowsum, totm, out);
}